// Round 1
// baseline (193.485 us; speedup 1.0000x reference)
//
#include <hip/hip_runtime.h>
#include <stdint.h>

#define TPB 256
#define ROWS_PB 256
#define TC 256
#define CS 8

__device__ __forceinline__ float waveReduceSum(float v){
#pragma unroll
  for (int o = 32; o > 0; o >>= 1) v += __shfl_down(v, o, 64);
  return v;
}

// 256-thread (4-wave) block sum. buf is __shared__ float[4], reusable across calls.
__device__ __forceinline__ float blockReduceSum(float v, float* buf){
  v = waveReduceSum(v);
  __syncthreads();
  if ((threadIdx.x & 63) == 0) buf[threadIdx.x >> 6] = v;
  __syncthreads();
  return buf[0] + buf[1] + buf[2] + buf[3];
}

// One direction of the chamfer/color min. Each block: ROWS_PB rows x cpc cols.
// Thread t: lane=t&63 owns rows {lane, lane+64, lane+128, lane+192}; wave w=t>>6
// processes column subset {4j+w} of each LDS tile (broadcast reads, conflict-free).
// Row results merged across the 4 waves in LDS, then atomicMin'd to global.
// Pack = (float_bits(dist)<<32)|col_idx : uint order == float order for d>=0,
// min picks smallest idx on ties (== jnp.argmin first-occurrence).
__global__ void __launch_bounds__(TPB) pass_min_kernel(
    const float* __restrict__ rows, const float* __restrict__ cols,
    unsigned long long* __restrict__ outPack, unsigned* __restrict__ outCol,
    int N, int cpc)
{
  __shared__ float4 ptsT[TC];
  __shared__ float4 colT[TC];
  __shared__ unsigned long long mPack[4 * ROWS_PB];
  __shared__ unsigned mCol[4 * ROWS_PB];

  const int b = blockIdx.y;
  const int rb = blockIdx.x / CS;
  const int chunk = blockIdx.x - rb * CS;
  const int t = threadIdx.x;
  const int lane = t & 63;
  const int w = t >> 6;
  const int rowBase = rb * ROWS_PB;
  const int colBase = chunk * cpc;

  float gx[4], gy[4], gz[4], hr[4], hg[4], hb[4];
  float bestD[4], bestC[4];
  int bestM[4];
#pragma unroll
  for (int k = 0; k < 4; k++){
    const float* p = rows + ((size_t)b * N + (rowBase + lane + 64 * k)) * 6;
    gx[k] = p[0]; gy[k] = p[1]; gz[k] = p[2];
    hr[k] = p[3]; hg[k] = p[4]; hb[k] = p[5];
    bestD[k] = 3.4e38f; bestC[k] = 3.4e38f; bestM[k] = 0;
  }

  for (int tb = 0; tb < cpc; tb += TC){
    const float* p = cols + ((size_t)b * N + (colBase + tb + t)) * 6;
    ptsT[t] = make_float4(p[0], p[1], p[2], 0.f);
    colT[t] = make_float4(p[3], p[4], p[5], 0.f);
    __syncthreads();
#pragma unroll 4
    for (int j = 0; j < TC / 4; j++){
      const int ml = j * 4 + w;
      const float4 pp = ptsT[ml];
      const float4 cc = colT[ml];
      const int mg = colBase + tb + ml;
#pragma unroll
      for (int k = 0; k < 4; k++){
        float dx = gx[k] - pp.x, dy = gy[k] - pp.y, dz = gz[k] - pp.z;
        float d = fmaf(dx, dx, fmaf(dy, dy, dz * dz));
        if (d < bestD[k]) { bestD[k] = d; bestM[k] = mg; }  // strict < keeps first idx
        float ex = hr[k] - cc.x, ey = hg[k] - cc.y, ez = hb[k] - cc.z;
        float e = fmaf(ex, ex, fmaf(ey, ey, ez * ez));
        bestC[k] = fminf(bestC[k], e);
      }
    }
    __syncthreads();
  }

#pragma unroll
  for (int k = 0; k < 4; k++){
    int r = lane + 64 * k;
    mPack[w * ROWS_PB + r] =
      ((unsigned long long)__float_as_uint(bestD[k]) << 32) | (unsigned)bestM[k];
    mCol[w * ROWS_PB + r] = __float_as_uint(bestC[k]);
  }
  __syncthreads();
  unsigned long long pk = mPack[t];
  unsigned cm = mCol[t];
#pragma unroll
  for (int i = 1; i < 4; i++){
    unsigned long long p2 = mPack[i * ROWS_PB + t];
    if (p2 < pk) pk = p2;
    unsigned c2 = mCol[i * ROWS_PB + t];
    if (c2 < cm) cm = c2;
  }
  size_t g = (size_t)b * N + rowBase + t;
  atomicMin(&outPack[g], pk);
  atomicMin(&outCol[g], cm);
}

// acc layout (floats): [0]=edge_length sum, [1..6]=Sn[b][c], [7..12]=Se[b][c], [13]=cos sum
__global__ void __launch_bounds__(TPB) edge_pass1(
    const float* __restrict__ preds, const float* __restrict__ normals,
    const int* __restrict__ edges, const unsigned long long* __restrict__ packS2F,
    float* __restrict__ acc, int N, int E)
{
  __shared__ float buf[4];
  int gid = blockIdx.x * TPB + threadIdx.x;
  int b = gid / E, e = gid - b * E;   // E % TPB == 0 -> whole block same b
  int e0 = edges[2 * e], e1 = edges[2 * e + 1];
  const float* p0 = preds + ((size_t)b * N + e0) * 6;
  const float* p1 = preds + ((size_t)b * N + e1) * 6;
  float ex = p0[0] - p1[0], ey = p0[1] - p1[1], ez = p0[2] - p1[2];
  float el = fabsf(ex) + fabsf(ey) + fabsf(ez);
  unsigned idx = (unsigned)packS2F[(size_t)b * N + e0];
  const float* nr = normals + ((size_t)b * N + idx) * 3;
  float n0 = nr[0], n1 = nr[1], n2 = nr[2];
  float t0 = truncf(ex), t1 = truncf(ey), t2 = truncf(ez);

  float s;
  s = blockReduceSum(el, buf);      if (threadIdx.x == 0) atomicAdd(&acc[0], s);
  s = blockReduceSum(n0 * n0, buf); if (threadIdx.x == 0) atomicAdd(&acc[1 + b * 3 + 0], s);
  s = blockReduceSum(n1 * n1, buf); if (threadIdx.x == 0) atomicAdd(&acc[1 + b * 3 + 1], s);
  s = blockReduceSum(n2 * n2, buf); if (threadIdx.x == 0) atomicAdd(&acc[1 + b * 3 + 2], s);
  s = blockReduceSum(t0 * t0, buf); if (threadIdx.x == 0) atomicAdd(&acc[7 + b * 3 + 0], s);
  s = blockReduceSum(t1 * t1, buf); if (threadIdx.x == 0) atomicAdd(&acc[7 + b * 3 + 1], s);
  s = blockReduceSum(t2 * t2, buf); if (threadIdx.x == 0) atomicAdd(&acc[7 + b * 3 + 2], s);
}

__global__ void __launch_bounds__(TPB) edge_pass2(
    const float* __restrict__ preds, const float* __restrict__ normals,
    const int* __restrict__ edges, const unsigned long long* __restrict__ packS2F,
    float* __restrict__ acc, int N, int E)
{
  __shared__ float buf[4];
  int gid = blockIdx.x * TPB + threadIdx.x;
  int b = gid / E, e = gid - b * E;
  int e0 = edges[2 * e], e1 = edges[2 * e + 1];
  const float* p0 = preds + ((size_t)b * N + e0) * 6;
  const float* p1 = preds + ((size_t)b * N + e1) * 6;
  float ex = p0[0] - p1[0], ey = p0[1] - p1[1], ez = p0[2] - p1[2];
  unsigned idx = (unsigned)packS2F[(size_t)b * N + e0];
  const float* nr = normals + ((size_t)b * N + idx) * 3;
  float n0 = nr[0], n1 = nr[1], n2 = nr[2];
  float t0 = truncf(ex), t1 = truncf(ey), t2 = truncf(ez);
  // _unit_axis1 normalizes over the E axis: per (b, channel) norms
  float r0 = 1.0f / (fmaxf(sqrtf(acc[1 + b * 3 + 0]), 1e-12f) * fmaxf(sqrtf(acc[7 + b * 3 + 0]), 1e-12f));
  float r1 = 1.0f / (fmaxf(sqrtf(acc[1 + b * 3 + 1]), 1e-12f) * fmaxf(sqrtf(acc[7 + b * 3 + 1]), 1e-12f));
  float r2 = 1.0f / (fmaxf(sqrtf(acc[1 + b * 3 + 2]), 1e-12f) * fmaxf(sqrtf(acc[7 + b * 3 + 2]), 1e-12f));
  float cosv = fabsf(n0 * t0 * r0 + n1 * t1 * r1 + n2 * t2 * r2);
  float s = blockReduceSum(cosv, buf);
  if (threadIdx.x == 0) atomicAdd(&acc[13], s);
}

__global__ void __launch_bounds__(TPB) final_reduce(
    const unsigned long long* __restrict__ packS2F,
    const unsigned long long* __restrict__ packF2S,
    const unsigned* __restrict__ colMin2, const unsigned* __restrict__ colMin1,
    const float* __restrict__ acc, float* __restrict__ out,
    int N, int BNtot, int E)
{
  __shared__ float buf[4];
  int t = threadIdx.x;
  float invN = 1.0f / (float)N;
  float s = 0.f;
  for (int i = t; i < BNtot; i += TPB){
    float s2f = __uint_as_float((unsigned)(packS2F[i] >> 32));
    float f2s = __uint_as_float((unsigned)(packF2S[i] >> 32));
    float c2 = __uint_as_float(colMin2[i]);
    float c1 = __uint_as_float(colMin1[i]);
    s += 3000.0f * invN * f2s + 1650.0f * invN * s2f + c1 + c2;
  }
  s = blockReduceSum(s, buf);
  if (t == 0){
    s += acc[0] * (300.0f / (float)E);
    s += acc[13] * (0.5f / (float)E);
    out[0] = s;
  }
}

extern "C" void kernel_launch(void* const* d_in, const int* in_sizes, int n_in,
                              void* d_out, int out_size, void* d_ws, size_t ws_size,
                              hipStream_t stream)
{
  const float* gts     = (const float*)d_in[0];
  const float* preds   = (const float*)d_in[1];
  const float* normals = (const float*)d_in[2];
  const int*   edges   = (const int*)d_in[3];

  const int B = 2;
  const int BNtot = in_sizes[2] / 3;   // B*N from gts_normals
  const int N = BNtot / B;
  const int E = in_sizes[3] / 2;

  char* ws = (char*)d_ws;
  unsigned long long* packS2F = (unsigned long long*)ws;                       // BN u64
  unsigned long long* packF2S = (unsigned long long*)(ws + (size_t)BNtot * 8); // BN u64
  unsigned* colMin2 = (unsigned*)(ws + (size_t)BNtot * 16);                    // BN u32
  unsigned* colMin1 = (unsigned*)(ws + (size_t)BNtot * 20);                    // BN u32
  float* acc = (float*)(ws + (size_t)BNtot * 24);                              // 16 f32

  // init: 0xFF == +inf sentinel for uint-ordered mins; zeros for accumulators
  hipMemsetAsync(ws, 0xFF, (size_t)BNtot * 24, stream);
  hipMemsetAsync(acc, 0, 64, stream);

  int cpc = N / CS;
  dim3 g1((N / ROWS_PB) * CS, B);
  // dist_s2f + idx_s2f (per gt, min over preds) and color min axis=2
  pass_min_kernel<<<g1, TPB, 0, stream>>>(gts, preds, packS2F, colMin2, N, cpc);
  // dist_f2s (per pred, min over gts) and color min axis=1
  pass_min_kernel<<<g1, TPB, 0, stream>>>(preds, gts, packF2S, colMin1, N, cpc);

  int nb = (B * E + TPB - 1) / TPB;
  edge_pass1<<<nb, TPB, 0, stream>>>(preds, normals, edges, packS2F, acc, N, E);
  edge_pass2<<<nb, TPB, 0, stream>>>(preds, normals, edges, packS2F, acc, N, E);

  final_reduce<<<1, TPB, 0, stream>>>(packS2F, packF2S, colMin2, colMin1, acc,
                                      (float*)d_out, N, BNtot, E);
}

// Round 2
// 119.044 us; speedup vs baseline: 1.6253x; 1.6253x over previous
//
#include <hip/hip_runtime.h>
#include <stdint.h>

#define TPB 256
#define ROWS_PB 256
#define TC 256
#define CS 8
#define FINAL_BLOCKS 64

typedef unsigned long long u64;
typedef unsigned int u32;

__device__ __forceinline__ float waveReduceSum(float v){
#pragma unroll
  for (int o = 32; o > 0; o >>= 1) v += __shfl_down(v, o, 64);
  return v;
}

__device__ __forceinline__ float blockReduceSum(float v, float* buf){
  v = waveReduceSum(v);
  __syncthreads();
  if ((threadIdx.x & 63) == 0) buf[threadIdx.x >> 6] = v;
  __syncthreads();
  return buf[0] + buf[1] + buf[2] + buf[3];
}

// One direction of the chamfer/color min, expanded form d = rx + ry - 2<x,y>.
// ry/rc staged in LDS float4.w (computed at stage time). Row side pre-negated
// (-2*coord) so inner point dist = 3 FMA. rx added + clamped >=0 at epilogue
// (before uint-ordered pack, so atomicMin order-isomorphism holds).
// NEED_IDX dir tracks argmin (cmp+2 cndmask, first-occurrence preserved);
// other dir is fmin-only (min3-friendly chains).
template<bool NEED_IDX>
__device__ __forceinline__ void pass_body(
    const float* __restrict__ rows, const float* __restrict__ cols,
    void* __restrict__ outPackV, u32* __restrict__ outCol, int N, int cpc)
{
  __shared__ float4 ptsT[TC];
  __shared__ float4 colT[TC];
  __shared__ u64 mPack[4 * TPB];
  __shared__ u32 mCol[4 * TPB];

  const int b = blockIdx.y;
  const int rb = blockIdx.x / CS;
  const int chunk = blockIdx.x - rb * CS;
  const int t = threadIdx.x;
  const int lane = t & 63;
  const int w = t >> 6;
  const int rowBase = rb * ROWS_PB;
  const int colBase = chunk * cpc;

  float ax[4], ay[4], az[4], rx[4];
  float cr[4], cg[4], cbl[4], rc[4];
  float bD[4], bC[4];
  int bM[4];
#pragma unroll
  for (int k = 0; k < 4; k++){
    const float* p = rows + ((size_t)b * N + (rowBase + lane + 64 * k)) * 6;
    float p0 = p[0], p1 = p[1], p2 = p[2], p3 = p[3], p4 = p[4], p5 = p[5];
    ax[k] = -2.f * p0; ay[k] = -2.f * p1; az[k] = -2.f * p2;
    rx[k] = fmaf(p0, p0, fmaf(p1, p1, p2 * p2));
    cr[k] = -2.f * p3; cg[k] = -2.f * p4; cbl[k] = -2.f * p5;
    rc[k] = fmaf(p3, p3, fmaf(p4, p4, p5 * p5));
    bD[k] = 3.4e38f; bC[k] = 3.4e38f; bM[k] = 0;
  }

  for (int tb = 0; tb < cpc; tb += TC){
    const float* p = cols + ((size_t)b * N + (colBase + tb + t)) * 6;
    float q0 = p[0], q1 = p[1], q2 = p[2], q3 = p[3], q4 = p[4], q5 = p[5];
    ptsT[t] = make_float4(q0, q1, q2, fmaf(q0, q0, fmaf(q1, q1, q2 * q2)));
    colT[t] = make_float4(q3, q4, q5, fmaf(q3, q3, fmaf(q4, q4, q5 * q5)));
    __syncthreads();
#pragma unroll 4
    for (int j = 0; j < TC / 4; j += 2){
      const int mlA = j * 4 + w;
      const int mlB = mlA + 4;
      const float4 pA = ptsT[mlA], pB = ptsT[mlB];
      const float4 cA = colT[mlA], cB = colT[mlB];
      const int gA = colBase + tb + mlA;
      const int gB = gA + 4;
#pragma unroll
      for (int k = 0; k < 4; k++){
        float tA = fmaf(ax[k], pA.x, fmaf(ay[k], pA.y, fmaf(az[k], pA.z, pA.w)));
        float tB = fmaf(ax[k], pB.x, fmaf(ay[k], pB.y, fmaf(az[k], pB.z, pB.w)));
        if (NEED_IDX){
          if (tA < bD[k]) { bD[k] = tA; bM[k] = gA; }  // strict <, lower idx first
          if (tB < bD[k]) { bD[k] = tB; bM[k] = gB; }
        } else {
          bD[k] = fminf(fminf(tA, tB), bD[k]);          // min3-friendly
        }
        float eA = fmaf(cr[k], cA.x, fmaf(cg[k], cA.y, fmaf(cbl[k], cA.z, cA.w)));
        float eB = fmaf(cr[k], cB.x, fmaf(cg[k], cB.y, fmaf(cbl[k], cB.z, cB.w)));
        bC[k] = fminf(fminf(eA, eB), bC[k]);
      }
    }
    __syncthreads();
  }

#pragma unroll
  for (int k = 0; k < 4; k++){
    int r = lane + 64 * k;
    float dv = fmaxf(bD[k] + rx[k], 0.f);   // clamp: expanded form can round <0
    float cv = fmaxf(bC[k] + rc[k], 0.f);
    mPack[w * TPB + r] = NEED_IDX
        ? (((u64)__float_as_uint(dv) << 32) | (u32)bM[k])
        : (u64)__float_as_uint(dv);
    mCol[w * TPB + r] = __float_as_uint(cv);
  }
  __syncthreads();
  u64 pk = mPack[t];
  u32 cm = mCol[t];
#pragma unroll
  for (int i = 1; i < 4; i++){
    u64 p2 = mPack[i * TPB + t]; if (p2 < pk) pk = p2;
    u32 c2 = mCol[i * TPB + t];  if (c2 < cm) cm = c2;
  }
  size_t g = (size_t)b * N + rowBase + t;
  if (NEED_IDX) atomicMin((u64*)outPackV + g, pk);
  else          atomicMin((u32*)outPackV + g, (u32)pk);
  atomicMin(&outCol[g], cm);
}

__global__ void __launch_bounds__(TPB) pass_all(
    const float* __restrict__ gts, const float* __restrict__ preds,
    u64* __restrict__ packS2F, u32* __restrict__ colMin2,
    u32* __restrict__ distF2S, u32* __restrict__ colMin1, int N, int cpc)
{
  if (blockIdx.z == 0) pass_body<true >(gts,  preds, packS2F, colMin2, N, cpc);
  else                 pass_body<false>(preds, gts,  distF2S, colMin1, N, cpc);
}

// acc layout (floats): [0]=edge_len sum, [1..6]=Sn[b][c], [7..12]=Se[b][c],
// [13]=cos sum, [14]=min-array weighted sum
__global__ void __launch_bounds__(TPB) edge_pass1(
    const float* __restrict__ preds, const float* __restrict__ normals,
    const int* __restrict__ edges, const u64* __restrict__ packS2F,
    float* __restrict__ acc, int N, int E)
{
  __shared__ float buf[7][4];
  int gid = blockIdx.x * TPB + threadIdx.x;
  int b = gid / E, e = gid - b * E;   // E % TPB == 0 -> block-uniform b
  int e0 = edges[2 * e], e1 = edges[2 * e + 1];
  const float* p0 = preds + ((size_t)b * N + e0) * 6;
  const float* p1 = preds + ((size_t)b * N + e1) * 6;
  float ex = p0[0] - p1[0], ey = p0[1] - p1[1], ez = p0[2] - p1[2];
  u32 idx = (u32)packS2F[(size_t)b * N + e0];
  const float* nr = normals + ((size_t)b * N + idx) * 3;
  float n0 = nr[0], n1 = nr[1], n2 = nr[2];
  float t0 = truncf(ex), t1 = truncf(ey), t2 = truncf(ez);
  float v[7] = { fabsf(ex) + fabsf(ey) + fabsf(ez),
                 n0 * n0, n1 * n1, n2 * n2, t0 * t0, t1 * t1, t2 * t2 };
  int lane = threadIdx.x & 63, w = threadIdx.x >> 6;
#pragma unroll
  for (int q = 0; q < 7; q++){
    float s = waveReduceSum(v[q]);
    if (lane == 0) buf[q][w] = s;
  }
  __syncthreads();
  if (threadIdx.x < 7){
    int q = threadIdx.x;
    float s = buf[q][0] + buf[q][1] + buf[q][2] + buf[q][3];
    int off = (q == 0) ? 0 : (q < 4 ? 1 + b * 3 + (q - 1) : 7 + b * 3 + (q - 4));
    atomicAdd(&acc[off], s);
  }
}

// blocks [0,nEdge): edge cosine pass; blocks [nEdge, nEdge+FINAL_BLOCKS):
// grid-stride weighted sum of the min arrays (passes are already complete).
__global__ void __launch_bounds__(TPB) edge2_and_sum(
    const float* __restrict__ preds, const float* __restrict__ normals,
    const int* __restrict__ edges, const u64* __restrict__ packS2F,
    const u32* __restrict__ distF2S, const u32* __restrict__ colMin2,
    const u32* __restrict__ colMin1, float* __restrict__ acc,
    int N, int E, int BNtot, int nEdge)
{
  __shared__ float buf[4];
  if ((int)blockIdx.x < nEdge){
    int gid = blockIdx.x * TPB + threadIdx.x;
    int b = gid / E, e = gid - b * E;
    int e0 = edges[2 * e], e1 = edges[2 * e + 1];
    const float* p0 = preds + ((size_t)b * N + e0) * 6;
    const float* p1 = preds + ((size_t)b * N + e1) * 6;
    float ex = p0[0] - p1[0], ey = p0[1] - p1[1], ez = p0[2] - p1[2];
    u32 idx = (u32)packS2F[(size_t)b * N + e0];
    const float* nr = normals + ((size_t)b * N + idx) * 3;
    float t0 = truncf(ex), t1 = truncf(ey), t2 = truncf(ez);
    // _unit_axis1 normalizes over the E axis: per (b,channel) norms from pass1
    float r0 = 1.0f / (fmaxf(sqrtf(acc[1 + b * 3 + 0]), 1e-12f) * fmaxf(sqrtf(acc[7 + b * 3 + 0]), 1e-12f));
    float r1 = 1.0f / (fmaxf(sqrtf(acc[1 + b * 3 + 1]), 1e-12f) * fmaxf(sqrtf(acc[7 + b * 3 + 1]), 1e-12f));
    float r2 = 1.0f / (fmaxf(sqrtf(acc[1 + b * 3 + 2]), 1e-12f) * fmaxf(sqrtf(acc[7 + b * 3 + 2]), 1e-12f));
    float cosv = fabsf(nr[0] * t0 * r0 + nr[1] * t1 * r1 + nr[2] * t2 * r2);
    float s = blockReduceSum(cosv, buf);
    if (threadIdx.x == 0) atomicAdd(&acc[13], s);
  } else {
    int sb = blockIdx.x - nEdge;
    float invN = 1.0f / (float)N;
    float s = 0.f;
    for (int i = sb * TPB + threadIdx.x; i < BNtot; i += FINAL_BLOCKS * TPB){
      float s2f = __uint_as_float((u32)(packS2F[i] >> 32));
      float f2s = __uint_as_float(distF2S[i]);
      s += 3000.0f * invN * f2s + 1650.0f * invN * s2f
         + __uint_as_float(colMin1[i]) + __uint_as_float(colMin2[i]);
    }
    s = blockReduceSum(s, buf);
    if (threadIdx.x == 0) atomicAdd(&acc[14], s);
  }
}

__global__ void combine_kernel(const float* __restrict__ acc,
                               float* __restrict__ out, int E)
{
  out[0] = acc[14] + acc[0] * (300.0f / (float)E) + acc[13] * (0.5f / (float)E);
}

extern "C" void kernel_launch(void* const* d_in, const int* in_sizes, int n_in,
                              void* d_out, int out_size, void* d_ws, size_t ws_size,
                              hipStream_t stream)
{
  const float* gts     = (const float*)d_in[0];
  const float* preds   = (const float*)d_in[1];
  const float* normals = (const float*)d_in[2];
  const int*   edges   = (const int*)d_in[3];

  const int B = 2;
  const int BNtot = in_sizes[2] / 3;   // B*N from gts_normals
  const int N = BNtot / B;
  const int E = in_sizes[3] / 2;

  char* ws = (char*)d_ws;
  u64* packS2F = (u64*)ws;                               // BN u64 (dist|idx)
  u32* distF2S = (u32*)(ws + (size_t)BNtot * 8);         // BN u32
  u32* colMin2 = (u32*)(ws + (size_t)BNtot * 12);        // BN u32
  u32* colMin1 = (u32*)(ws + (size_t)BNtot * 16);        // BN u32
  float* acc   = (float*)(ws + (size_t)BNtot * 20);      // 16 f32

  hipMemsetAsync(ws, 0xFF, (size_t)BNtot * 20, stream);  // +inf sentinels
  hipMemsetAsync(acc, 0, 64, stream);

  int cpc = N / CS;
  dim3 gp((N / ROWS_PB) * CS, B, 2);   // both directions in one launch
  pass_all<<<gp, TPB, 0, stream>>>(gts, preds, packS2F, colMin2, distF2S, colMin1, N, cpc);

  int nEdge = (B * E) / TPB;
  edge_pass1<<<nEdge, TPB, 0, stream>>>(preds, normals, edges, packS2F, acc, N, E);
  edge2_and_sum<<<nEdge + FINAL_BLOCKS, TPB, 0, stream>>>(
      preds, normals, edges, packS2F, distF2S, colMin2, colMin1, acc, N, E, BNtot, nEdge);
  combine_kernel<<<1, 1, 0, stream>>>(acc, (float*)d_out, E);
}